// Round 15
// baseline (338.471 us; speedup 1.0000x reference)
//
#include <hip/hip_runtime.h>

#define NHALF 32
#define NDIM  64
#define NHID  256
#define NPAR  736   // (3K-1)*HALF = 23*32

typedef unsigned short u16;
typedef unsigned int   u32;
typedef __attribute__((ext_vector_type(8))) short short8;   // 8 bf16 = 4 VGPR
typedef __attribute__((ext_vector_type(4))) float f32x4;

__device__ __forceinline__ float bf2f(u16 h){ return __uint_as_float(((u32)h) << 16); }
__device__ __forceinline__ u16 f2bf(float f){
  u32 u = __float_as_uint(f);
  u += 0x7FFFu + ((u >> 16) & 1u);   // round-to-nearest-even
  return (u16)(u >> 16);
}
__device__ __forceinline__ float frcp(float x){ return __builtin_amdgcn_rcpf(x); }
__device__ __forceinline__ float tanh_fast(float x){
  x = fminf(15.f, fmaxf(-15.f, x));
  float e = __expf(2.f * x);
  return 1.f - 2.f * frcp(e + 1.f);
}

// h-buffer addressing (unchanged from R14, HW-validated)
__device__ __forceinline__ int hoff(int row, int col){
  return row * 264 + (col ^ (((row >> 2) & 3) << 3));
}

// ---------------- Fused MLP + spline.
// Phase A (identical to R14 mlp_fused): pr rows for this block's 128 rows.
// Phase B: after __syncthreads (drains vmcnt -> own pr writes L2-visible,
// never L1-cached before first read), run the spline for the same 128 rows,
// params read back L2-hot. Spline math byte-identical to R5-R14 spline_k.
// XMLP: MLP input col offset; XSPL: spline transform col; PHASE: logdet chain.
template<int XMLP, int XSPL, int PHASE>
__global__ __launch_bounds__(256, 2)
void mlp_spline(const float* __restrict__ Xm,   // MLP input [N][64] fp32
                const float* __restrict__ Xo,   // original x [N][64] fp32
                const u16* __restrict__ w0t,    // [256][32]  n-major
                const u16* __restrict__ w1t,    // [256][256] n-major
                const u16* __restrict__ w2t,    // [768][256] n-major (rows>=736 zero)
                const float* __restrict__ b0, const float* __restrict__ b1,
                const float* __restrict__ b2,
                u16* __restrict__ pr,           // [N][736] scratch
                float* __restrict__ out,        // [N][64] (d_out)
                float* __restrict__ ldp,        // partial logdet (ws)
                float* __restrict__ ldout)      // final logdet (d_out + N*64)
{
  __shared__ __align__(16) u16 hb[128 * 264];  // 67584 B
  const int t = threadIdx.x, lane = t & 63, w = t >> 6;
  const int lm = lane & 15, lk = lane >> 4;
  const int row0 = blockIdx.x * 128;
  const int cb = w * 64;

  f32x4 acc[8][4];
  const f32x4 zf = (f32x4){0.f, 0.f, 0.f, 0.f};

  // ---------- L0: h1 = tanh(x @ W0t^T + b0), K=32
  {
    short8 a[8];
    #pragma unroll
    for (int mf = 0; mf < 8; mf++){
      const float* xp = Xm + (size_t)(row0 + mf * 16 + lm) * NDIM + XMLP + lk * 8;
      float4 v0 = *(const float4*)xp;
      float4 v1 = *(const float4*)(xp + 4);
      u16 tmp[8];
      tmp[0] = f2bf(v0.x); tmp[1] = f2bf(v0.y); tmp[2] = f2bf(v0.z); tmp[3] = f2bf(v0.w);
      tmp[4] = f2bf(v1.x); tmp[5] = f2bf(v1.y); tmp[6] = f2bf(v1.z); tmp[7] = f2bf(v1.w);
      a[mf] = *(const short8*)tmp;
    }
    #pragma unroll
    for (int nf = 0; nf < 4; nf++){
      short8 b = *(const short8*)(w0t + (size_t)(cb + nf * 16 + lm) * 32 + lk * 8);
      #pragma unroll
      for (int mf = 0; mf < 8; mf++)
        acc[mf][nf] = __builtin_amdgcn_mfma_f32_16x16x32_bf16(a[mf], b, zf, 0, 0, 0);
    }
    #pragma unroll
    for (int nf = 0; nf < 4; nf++){
      int col = cb + nf * 16 + lm;
      float bs = b0[col];
      #pragma unroll
      for (int mf = 0; mf < 8; mf++)
        #pragma unroll
        for (int r = 0; r < 4; r++)
          hb[hoff(mf * 16 + lk * 4 + r, col)] = f2bf(tanh_fast(acc[mf][nf][r] + bs));
    }
  }
  __syncthreads();

  // ---------- L1: h2 = tanh(h1 @ W1t^T + b1), K=256
  #pragma unroll
  for (int mf = 0; mf < 8; mf++)
    #pragma unroll
    for (int nf = 0; nf < 4; nf++) acc[mf][nf] = zf;
  for (int ks = 0; ks < 8; ks++){
    short8 av[8], bv[4];
    #pragma unroll
    for (int mf = 0; mf < 8; mf++)
      av[mf] = *(const short8*)(hb + hoff(mf * 16 + lm, ks * 32 + lk * 8));
    #pragma unroll
    for (int nf = 0; nf < 4; nf++)
      bv[nf] = *(const short8*)(w1t + (size_t)(cb + nf * 16 + lm) * 256 + ks * 32 + lk * 8);
    #pragma unroll
    for (int mf = 0; mf < 8; mf++)
      #pragma unroll
      for (int nf = 0; nf < 4; nf++)
        acc[mf][nf] = __builtin_amdgcn_mfma_f32_16x16x32_bf16(av[mf], bv[nf], acc[mf][nf], 0, 0, 0);
  }
  __syncthreads();
  {
    #pragma unroll
    for (int nf = 0; nf < 4; nf++){
      int col = cb + nf * 16 + lm;
      float bs = b1[col];
      #pragma unroll
      for (int mf = 0; mf < 8; mf++)
        #pragma unroll
        for (int r = 0; r < 4; r++)
          hb[hoff(mf * 16 + lk * 4 + r, col)] = f2bf(tanh_fast(acc[mf][nf][r] + bs));
    }
  }
  __syncthreads();

  // ---------- L2: pr = h2 @ W2t^T + b2, 768 cols in 3 passes/wave
  #pragma unroll 1
  for (int p = 0; p < 3; p++){
    const int cb2 = p * 256 + w * 64;
    #pragma unroll
    for (int mf = 0; mf < 8; mf++)
      #pragma unroll
      for (int nf = 0; nf < 4; nf++) acc[mf][nf] = zf;
    for (int ks = 0; ks < 8; ks++){
      short8 av[8], bv[4];
      #pragma unroll
      for (int mf = 0; mf < 8; mf++)
        av[mf] = *(const short8*)(hb + hoff(mf * 16 + lm, ks * 32 + lk * 8));
      #pragma unroll
      for (int nf = 0; nf < 4; nf++)
        bv[nf] = *(const short8*)(w2t + (size_t)(cb2 + nf * 16 + lm) * 256 + ks * 32 + lk * 8);
      #pragma unroll
      for (int mf = 0; mf < 8; mf++)
        #pragma unroll
        for (int nf = 0; nf < 4; nf++)
          acc[mf][nf] = __builtin_amdgcn_mfma_f32_16x16x32_bf16(av[mf], bv[nf], acc[mf][nf], 0, 0, 0);
    }
    #pragma unroll
    for (int nf = 0; nf < 4; nf++){
      int col = cb2 + nf * 16 + lm;
      if (col < NPAR){
        float bs = b2[col];
        #pragma unroll
        for (int mf = 0; mf < 8; mf++)
          #pragma unroll
          for (int r = 0; r < 4; r++)
            pr[(size_t)(row0 + mf * 16 + lk * 4 + r) * NPAR + col] = f2bf(acc[mf][nf][r] + bs);
      }
    }
  }
  __syncthreads();   // drains vmcnt: this block's pr writes are L2-visible

  // ---------- spline for this block's 128 rows (math identical to spline_k)
  const int d  = t & 31;
  const int sg = t >> 5;                 // 8 samples in flight
  #pragma unroll 1
  for (int it = 0; it < 16; it++){
    const int s = row0 + it * 8 + sg;
    const u16* pp = pr + (size_t)s * NPAR + d * 23;
    float p[23];
    #pragma unroll
    for (int e = 0; e < 23; e++) p[e] = bf2f(pp[e]);

    float W6[8], H6[8];
    {
      float m = p[0];
      #pragma unroll
      for (int i = 1; i < 8; i++) m = fmaxf(m, p[i]);
      float sm = 0.f;
      #pragma unroll
      for (int i = 0; i < 8; i++){ W6[i] = __expf(p[i] - m); sm += W6[i]; }
      float r = 6.f * frcp(sm);
      #pragma unroll
      for (int i = 0; i < 8; i++) W6[i] *= r;
    }
    {
      float m = p[8];
      #pragma unroll
      for (int i = 1; i < 8; i++) m = fmaxf(m, p[8 + i]);
      float sm = 0.f;
      #pragma unroll
      for (int i = 0; i < 8; i++){ H6[i] = __expf(p[8 + i] - m); sm += H6[i]; }
      float r = 6.f * frcp(sm);
      #pragma unroll
      for (int i = 0; i < 8; i++) H6[i] *= r;
    }

    float wd[8], cumw[9];
    {
      float sm = 0.f;
      #pragma unroll
      for (int i = 0; i < 8; i++){ wd[i] = __expf(W6[i]); sm += wd[i]; }
      float r = 0.992f * frcp(sm);
      #pragma unroll
      for (int i = 0; i < 8; i++) wd[i] = 0.001f + wd[i] * r;
    }
    cumw[0] = -3.f;
    { float run = 0.f;
      #pragma unroll
      for (int i = 0; i < 8; i++){ run += wd[i]; cumw[i + 1] = 6.f * run - 3.f; } }
    cumw[8] = 3.f;
    #pragma unroll
    for (int i = 0; i < 8; i++) wd[i] = cumw[i + 1] - cumw[i];

    float hg[8], cumh[9];
    {
      float sm = 0.f;
      #pragma unroll
      for (int i = 0; i < 8; i++){ hg[i] = __expf(H6[i]); sm += hg[i]; }
      float r = 0.992f * frcp(sm);
      #pragma unroll
      for (int i = 0; i < 8; i++) hg[i] = 0.001f + hg[i] * r;
    }
    cumh[0] = -3.f;
    { float run = 0.f;
      #pragma unroll
      for (int i = 0; i < 8; i++){ run += hg[i]; cumh[i + 1] = 6.f * run - 3.f; } }
    cumh[8] = 3.f;
    #pragma unroll
    for (int i = 0; i < 8; i++) hg[i] = cumh[i + 1] - cumh[i];

    float dv[9];
    dv[0] = 1.f; dv[8] = 1.f;
    #pragma unroll
    for (int j = 0; j < 7; j++){
      float xx  = p[16 + j];
      float z   = __expf(-fabsf(xx));
      float sel = (xx >= 0.f) ? z : 1.f;
      dv[j + 1] = 0.001f + fmaxf(xx, 0.f) + __logf(1.f + z + sel);
    }

    const float xv  = Xo[(size_t)s * NDIM + XSPL + d];
    const float xin = fminf(3.f, fmaxf(-3.f, xv));

    int b = 0;
    #pragma unroll
    for (int j = 1; j < 8; j++) b += (xin >= cumw[j]) ? 1 : 0;

    float in_cw = 0.f, in_w = 0.f, in_ch = 0.f, in_h = 0.f, in_d = 0.f, in_d1 = 0.f;
    #pragma unroll
    for (int j = 0; j < 8; j++){
      if (j == b){ in_cw = cumw[j]; in_w = wd[j]; in_ch = cumh[j];
                   in_h = hg[j];  in_d = dv[j]; in_d1 = dv[j + 1]; }
    }

    float rw    = frcp(in_w);
    float th    = (xin - in_cw) * rw;
    float tt    = th * (1.f - th);
    float delta = in_h * rw;
    float numer = in_h * (delta * th * th + in_d * tt);
    float denom = delta + (in_d + in_d1 - 2.f * delta) * tt;
    float rden  = frcp(denom);
    float outv  = in_ch + numer * rden;
    float omt   = 1.f - th;
    float dnum  = delta * delta * (in_d1 * th * th + 2.f * delta * tt + in_d * omt * omt);
    float lad   = __logf(dnum * rden * rden);

    bool inside = (xv >= -3.f) && (xv <= 3.f);
    outv = inside ? outv : xv;
    lad  = inside ? lad  : 0.f;

    out[(size_t)s * NDIM + XSPL + d] = outv;

    float v = lad;
    #pragma unroll
    for (int mm = 1; mm < 32; mm <<= 1) v += __shfl_xor(v, mm, 64);
    if (d == 0){
      if (PHASE == 0) ldp[s] = v;
      else            ldout[s] = ldp[s] + v;
    }
  }
}

// All three weight conversions in one launch (unchanged).
__global__ __launch_bounds__(256)
void wconv3_k(const float* __restrict__ W0, const float* __restrict__ W1,
              const float* __restrict__ W2,
              u16* __restrict__ w0t, u16* __restrict__ w1t, u16* __restrict__ w2t){
  int tid = blockIdx.x * 256 + threadIdx.x;
  if (tid < 8192){
    int n = tid >> 5, k = tid & 31;
    w0t[tid] = f2bf(W0[(size_t)k * 256 + n]);
  } else if (tid < 73728){
    int id = tid - 8192; int n = id >> 8, k = id & 255;
    w1t[id] = f2bf(W1[(size_t)k * 256 + n]);
  } else if (tid < 270336){
    int id = tid - 73728; int n = id >> 8, k = id & 255;
    w2t[id] = (n < 736) ? f2bf(W2[(size_t)k * 736 + n]) : (u16)0;
  }
}

extern "C" void kernel_launch(void* const* d_in, const int* in_sizes, int n_in,
                              void* d_out, int out_size, void* d_ws, size_t ws_size,
                              hipStream_t stream)
{
  const float* x    = (const float*)d_in[0];
  const float* f1w0 = (const float*)d_in[1];
  const float* f1b0 = (const float*)d_in[2];
  const float* f1w1 = (const float*)d_in[3];
  const float* f1b1 = (const float*)d_in[4];
  const float* f1w2 = (const float*)d_in[5];
  const float* f1b2 = (const float*)d_in[6];
  const float* f2w0 = (const float*)d_in[7];
  const float* f2b0 = (const float*)d_in[8];
  const float* f2w1 = (const float*)d_in[9];
  const float* f2b1 = (const float*)d_in[10];
  const float* f2w2 = (const float*)d_in[11];
  const float* f2b2 = (const float*)d_in[12];

  const int N = in_sizes[0] / NDIM;   // 65536
  float* out = (float*)d_out;
  float* ldout = out + (size_t)N * NDIM;

  // ws: pr (N*736 bf16) | ld1 (N f32) | w0t | w1t | w2t
  u16* pr = (u16*)d_ws;
  float* ld1 = (float*)(pr + (size_t)N * NPAR);
  u16* w0t = (u16*)(ld1 + N);          // 256 x 32
  u16* w1t = w0t + 256 * 32;           // 256 x 256
  u16* w2t = w1t + 256 * 256;          // 768 x 256 (rows 736.. zero)

  dim3 blk(256);
  dim3 gm(N / 128);                    // 512 blocks
  dim3 gw(1056);

  // ---- coupling 1: f1(x[:, :32]) -> transform upper (xcol 32), logdet partial
  wconv3_k<<<gw, blk, 0, stream>>>(f1w0, f1w1, f1w2, w0t, w1t, w2t);
  mlp_spline<0, NHALF, 0><<<gm, blk, 0, stream>>>(x, x, w0t, w1t, w2t,
                                                  f1b0, f1b1, f1b2,
                                                  pr, out, ld1, ldout);

  // ---- coupling 2: f2(out[:, 32:]) -> transform lower (xcol 0), logdet final
  wconv3_k<<<gw, blk, 0, stream>>>(f2w0, f2w1, f2w2, w0t, w1t, w2t);
  mlp_spline<NHALF, 0, 1><<<gm, blk, 0, stream>>>(out, x, w0t, w1t, w2t,
                                                  f2b0, f2b1, f2b2,
                                                  pr, out, ld1, ldout);
}